// Round 5
// baseline (1636.997 us; speedup 1.0000x reference)
//
#include <hip/hip_runtime.h>
#include <cstdint>
#include <cstddef>

#define N_NODES  50000
#define N_GRAPHS 32
#define NODE_F   16
#define GLOBAL_F 2
#define HID      300
#define LAT      100
#define N_EDGES  800000

#define HIDP 320            // padded K / hidden (multiple of 32)
#define LATP 128            // padded GEMM2 output cols
#define NCT1 (HIDP/16)      // 20 col-tiles GEMM1
#define NCT2 (LATP/16)      // 8  col-tiles GEMM2
#define NKS  (HIDP/32)      // 10 k-steps
#define EPB  96             // edges per block (6 row-tiles of 16)
#define NRT  6
#define ROWP 98             // padded row count in chunked LDS layout
#define HSFS 132            // fp32 spill row stride (bank skew)

typedef __bf16 bf16x8 __attribute__((ext_vector_type(8)));
typedef float  f32x4  __attribute__((ext_vector_type(4)));

__device__ __forceinline__ float relu_f(float x){ return fmaxf(x, 0.f); }

__device__ __forceinline__ unsigned short f2bf(float x){   // RNE, for prep kernels
  unsigned int u = __float_as_uint(x);
  u = (u + 0x7FFFu + ((u >> 16) & 1u)) >> 16;
  return (unsigned short)u;
}
__device__ __forceinline__ unsigned short f2bf_hw(float x){ // hot path: hw convert
  __bf16 h = (__bf16)x;
  return __builtin_bit_cast(unsigned short, h);
}
__device__ __forceinline__ float bf2f(unsigned int h){
  return __uint_as_float(h << 16);
}

__global__ void zero_kernel(float* __restrict__ p, int n){
  int i = blockIdx.x*blockDim.x + threadIdx.x;
  if (i < n) p[i] = 0.f;
}

__global__ void hist_kernel(const int* __restrict__ ei, int* __restrict__ hist){
  int e = blockIdx.x*blockDim.x + threadIdx.x;
  if (e < N_EDGES) atomicAdd(&hist[ei[N_EDGES + e]], 1);
}

// single-block exclusive scan of hist -> woff (write cursor per node)
__global__ __launch_bounds__(256) void scan_kernel(const int* __restrict__ hist,
                                                   int* __restrict__ woff){
  __shared__ int part[256];
  const int t = threadIdx.x;
  const int CH = (N_NODES + 255) / 256;
  const int lo = t*CH, hi = (lo + CH < N_NODES) ? lo + CH : N_NODES;
  int s = 0;
  for (int i = lo; i < hi; ++i) s += hist[i];
  part[t] = s;
  __syncthreads();
  for (int d = 1; d < 256; d <<= 1){
    int v = (t >= d) ? part[t-d] : 0;
    __syncthreads();
    part[t] += v;
    __syncthreads();
  }
  int run = (t == 0) ? 0 : part[t-1];
  for (int i = lo; i < hi; ++i){ woff[i] = run; run += hist[i]; }
}

// counting-sort scatter: edges grouped by dst
__global__ void sort_kernel(const int* __restrict__ ei, int* __restrict__ woff,
                            int* __restrict__ es, int* __restrict__ ed){
  int e = blockIdx.x*blockDim.x + threadIdx.x;
  if (e < N_EDGES){
    int s = ei[e], d = ei[N_EDGES + e];
    int pos = atomicAdd(&woff[d], 1);
    es[pos] = s; ed[pos] = d;
  }
}

// graph start offsets from sorted batch
__global__ void gstart_kernel(const int* __restrict__ batch, int* __restrict__ gstart){
  int n = blockIdx.x*blockDim.x + threadIdx.x;
  if (n < N_NODES){
    int b = batch[n];
    if (n == 0){ for (int g = 0; g <= b; ++g) gstart[g] = 0; }
    else {
      int bp = batch[n-1];
      for (int g = bp+1; g <= b; ++g) gstart[g] = n;
    }
    if (n == N_NODES-1){ for (int g = b+1; g <= N_GRAPHS; ++g) gstart[g] = N_NODES; }
  }
}

__device__ __forceinline__ void pack_one(const float* __restrict__ w, int K, int N,
                                         int nct, unsigned short* __restrict__ out, int i){
  int j  = i & 7;
  int l  = (i >> 3) & 63;
  int t  = i >> 9;
  int ct = t % nct, ks = t / nct;
  int n = ct*16 + (l & 15);
  int k = ks*32 + ((l >> 4) << 3) + j;
  float v = (k < K && n < N) ? w[(size_t)k*N + n] : 0.f;
  out[i] = f2bf(v);
}

#define W2F_ELEMS (NKS*NCT1*512)   /* 102400 */
#define W3F_ELEMS (NKS*NCT2*512)   /* 40960  */

// all four edge-layer weight packs in one launch
__global__ void pack_all(const float* __restrict__ w2a, const float* __restrict__ w3a,
                         const float* __restrict__ w2b, const float* __restrict__ w3b,
                         unsigned short* __restrict__ o2a, unsigned short* __restrict__ o3a,
                         unsigned short* __restrict__ o2b, unsigned short* __restrict__ o3b){
  int i = blockIdx.x*blockDim.x + threadIdx.x;
  if (i < W2F_ELEMS) pack_one(w2a, HID, HID, NCT1, o2a, i);
  else if (i < W2F_ELEMS + W3F_ELEMS) pack_one(w3a, HID, LAT, NCT2, o3a, i - W2F_ELEMS);
  else if (i < 2*W2F_ELEMS + W3F_ELEMS) pack_one(w2b, HID, HID, NCT1, o2b, i - W2F_ELEMS - W3F_ELEMS);
  else if (i < 2*W2F_ELEMS + 2*W3F_ELEMS) pack_one(w3b, HID, LAT, NCT2, o3b, i - 2*W2F_ELEMS - W3F_ELEMS);
}

// Pack W' = [W_top - W_bot | W_bot] from w1[2F][HID] into frag order, N'=640
template<int F>
__global__ void pack_w1frag(const float* __restrict__ w1,
                            unsigned short* __restrict__ out, int total){
  int i = blockIdx.x*blockDim.x + threadIdx.x;
  if (i >= total) return;
  int j  = i & 7;
  int l  = (i >> 3) & 63;
  int t  = i >> 9;
  int ct = t % 40, ks = t / 40;
  int n = ct*16 + (l & 15);
  int k = ks*32 + ((l >> 4) << 3) + j;
  float v = 0.f;
  if (k < F){
    if (n < HIDP){ if (n < HID) v = w1[(size_t)k*HID + n] - w1[(size_t)(F+k)*HID + n]; }
    else { int nn = n - HIDP; if (nn < HID) v = w1[(size_t)(F+k)*HID + nn]; }
  }
  out[i] = f2bf(v);
}

__global__ void pad_bias4(const float* __restrict__ a0, const float* __restrict__ a1,
                          const float* __restrict__ a2, const float* __restrict__ a3,
                          float* __restrict__ o0, float* __restrict__ o1,
                          float* __restrict__ o2, float* __restrict__ o3){
  int i = blockIdx.x*blockDim.x + threadIdx.x;
  if (i < HIDP){
    o0[i] = (i < HID) ? a0[i] : 0.f;
    o1[i] = (i < HID) ? a1[i] : 0.f;
    o2[i] = (i < HID) ? a2[i] : 0.f;
    o3[i] = (i < HID) ? a3[i] : 0.f;
  }
}

// x f32[N,16] -> xb bf16[N,32] zero-padded
__global__ void cvt_x0(const float* __restrict__ x, unsigned short* __restrict__ xb){
  int i = blockIdx.x*blockDim.x + threadIdx.x;
  if (i < N_NODES*32){
    int n = i >> 5, c = i & 31;
    xb[i] = (c < NODE_F) ? f2bf(x[(size_t)n*NODE_F + c]) : 0;
  }
}

// node-level GEMM: [64 x KPAD] @ [KPAD x 640] -> Ub|Vb bf16
template<int KPAD>
__global__ __launch_bounds__(256) void node_gemm(
    const unsigned short* __restrict__ xb, const unsigned short* __restrict__ wf,
    unsigned short* __restrict__ Ub, unsigned short* __restrict__ Vb){
  constexpr int NCH = KPAD/8;
  __shared__ __align__(16) unsigned short at[NCH][66][8];
  const int tid = threadIdx.x;
  const int n0 = blockIdx.x*64;
  for (int i = tid; i < 64*NCH; i += 256){
    int row = i / NCH, c = i % NCH;
    int n = n0 + row; if (n >= N_NODES) n = N_NODES-1;
    *(uint4*)&at[c][row][0] = *(const uint4*)&xb[(size_t)n*KPAD + c*8];
  }
  __syncthreads();
  const int wave = tid >> 6, l = tid & 63;
  const int lrow = l & 15, lq = l >> 4;
  f32x4 acc[4][10];
  #pragma unroll
  for (int rt = 0; rt < 4; ++rt)
    #pragma unroll
    for (int c = 0; c < 10; ++c)
      acc[rt][c] = (f32x4){0.f,0.f,0.f,0.f};
  for (int ks = 0; ks < KPAD/32; ++ks){
    bf16x8 a[4];
    #pragma unroll
    for (int rt = 0; rt < 4; ++rt)
      a[rt] = __builtin_bit_cast(bf16x8, *(const uint4*)&at[4*ks + lq][16*rt + lrow][0]);
    #pragma unroll
    for (int c = 0; c < 10; ++c){
      int ct = wave*10 + c;
      bf16x8 b = __builtin_bit_cast(bf16x8,
                   *(const uint4*)&wf[(((size_t)(ks*40 + ct)) << 9) + l*8]);
      #pragma unroll
      for (int rt = 0; rt < 4; ++rt)
        acc[rt][c] = __builtin_amdgcn_mfma_f32_16x16x32_bf16(a[rt], b, acc[rt][c], 0, 0, 0);
    }
  }
  #pragma unroll
  for (int c = 0; c < 10; ++c){
    int col = (wave*10 + c)*16 + lrow;
    #pragma unroll
    for (int rt = 0; rt < 4; ++rt){
      #pragma unroll
      for (int r = 0; r < 4; ++r){
        int n = n0 + rt*16 + lq*4 + r;
        if (n < N_NODES){
          unsigned short hv = f2bf_hw(acc[rt][c][r]);
          if (col < HIDP) Ub[(size_t)n*HIDP + col] = hv;
          else            Vb[(size_t)n*HIDP + col - HIDP] = hv;
        }
      }
    }
  }
}

// Per 96-edge tile (edges sorted by dst): gather h1 -> LDS chunked; GEMM1; h2; GEMM2;
// spill C2 to LDS fp32; block-level run-compressed atomic scatter.
__global__ __launch_bounds__(256, 2) void edge_mfma(
    const int* __restrict__ es, const int* __restrict__ ed,
    const unsigned short* __restrict__ U, const unsigned short* __restrict__ V,
    const float* __restrict__ b1p, const unsigned short* __restrict__ w2f,
    const float* __restrict__ b2p, const unsigned short* __restrict__ w3f,
    float* __restrict__ nodeacc){
  __shared__ __align__(16) unsigned char smem[(HIDP/8)*ROWP*8*2];  // 62,720 B
  __shared__ int sdst[EPB];
  __shared__ int sflag[EPB];
  unsigned short* hsb = (unsigned short*)smem;       // [40][ROWP][8] bf16 chunked
  float*          hsf = (float*)smem;                // [96][HSFS] fp32 spill (phase 2)
  #define HS(c,row) (hsb + (((c)*ROWP + (row)) << 3))

  const int tid = threadIdx.x;
  const int e0 = blockIdx.x * EPB;
  const int nvalid = (N_EDGES - e0 < EPB) ? (N_EDGES - e0) : EPB;
  if (tid < EPB) sdst[tid] = (tid < nvalid) ? ed[e0 + tid] : -1;

  // ---- gather + h1: 96 edges x 40 chunks = 3840 slots, 15 iters ----
  #pragma unroll
  for (int it = 0; it < 15; ++it){
    int idx = tid + it*256;
    int e = idx / 40;
    int c = idx - e*40;
    int eg = e0 + e; if (eg >= N_EDGES) eg = N_EDGES - 1;
    const int dn = ed[eg], sn = es[eg];
    const uint4 uu = *(const uint4*)&U[(size_t)dn*HIDP + c*8];
    const uint4 vv = *(const uint4*)&V[(size_t)sn*HIDP + c*8];
    const float4 bl = *(const float4*)&b1p[c*8];
    const float4 bh = *(const float4*)&b1p[c*8 + 4];
    const unsigned int uarr[4] = {uu.x, uu.y, uu.z, uu.w};
    const unsigned int varr[4] = {vv.x, vv.y, vv.z, vv.w};
    const float barr[8] = {bl.x, bl.y, bl.z, bl.w, bh.x, bh.y, bh.z, bh.w};
    unsigned int ou[4];
    #pragma unroll
    for (int q = 0; q < 4; ++q){
      float f0 = relu_f(bf2f(uarr[q] & 0xFFFFu) + bf2f(varr[q] & 0xFFFFu) + barr[2*q]);
      float f1 = relu_f(bf2f(uarr[q] >> 16)     + bf2f(varr[q] >> 16)     + barr[2*q+1]);
      ou[q] = (unsigned int)f2bf_hw(f0) | ((unsigned int)f2bf_hw(f1) << 16);
    }
    *(uint4*)HS(c, e) = make_uint4(ou[0], ou[1], ou[2], ou[3]);
  }
  __syncthreads();

  const int wave = tid >> 6, l = tid & 63;
  const int lrow = l & 15, lq = l >> 4;

  // ---- GEMM1: [96 x 320] = h1 @ w2 ----
  f32x4 acc1[NRT][5];
  #pragma unroll
  for (int rt = 0; rt < NRT; ++rt)
    #pragma unroll
    for (int c = 0; c < 5; ++c)
      acc1[rt][c] = (f32x4){0.f,0.f,0.f,0.f};
  for (int ks = 0; ks < NKS; ++ks){
    bf16x8 a[NRT];
    #pragma unroll
    for (int rt = 0; rt < NRT; ++rt)
      a[rt] = __builtin_bit_cast(bf16x8, *(const uint4*)HS(4*ks + lq, 16*rt + lrow));
    #pragma unroll
    for (int c = 0; c < 5; ++c){
      int ct = wave*5 + c;
      bf16x8 b = __builtin_bit_cast(bf16x8,
                   *(const uint4*)&w2f[(((size_t)(ks*NCT1 + ct)) << 9) + l*8]);
      #pragma unroll
      for (int rt = 0; rt < NRT; ++rt)
        acc1[rt][c] = __builtin_amdgcn_mfma_f32_16x16x32_bf16(a[rt], b, acc1[rt][c], 0, 0, 0);
    }
  }
  __syncthreads();   // all h1 reads done

  // ---- epilogue1: h2 = relu(C1 + b2) -> hs ----
  #pragma unroll
  for (int c = 0; c < 5; ++c){
    int col = (wave*5 + c)*16 + lrow;
    float b2v = b2p[col];
    #pragma unroll
    for (int rt = 0; rt < NRT; ++rt){
      #pragma unroll
      for (int r = 0; r < 4; ++r){
        int row = rt*16 + lq*4 + r;
        HS(col >> 3, row)[col & 7] = f2bf_hw(relu_f(acc1[rt][c][r] + b2v));
      }
    }
  }
  __syncthreads();

  // ---- GEMM2: [96 x 128] = h2 @ w3 ----
  f32x4 acc2[NRT][2];
  #pragma unroll
  for (int rt = 0; rt < NRT; ++rt)
    #pragma unroll
    for (int c = 0; c < 2; ++c)
      acc2[rt][c] = (f32x4){0.f,0.f,0.f,0.f};
  for (int ks = 0; ks < NKS; ++ks){
    bf16x8 a[NRT];
    #pragma unroll
    for (int rt = 0; rt < NRT; ++rt)
      a[rt] = __builtin_bit_cast(bf16x8, *(const uint4*)HS(4*ks + lq, 16*rt + lrow));
    #pragma unroll
    for (int c = 0; c < 2; ++c){
      int ct = wave*2 + c;
      bf16x8 b = __builtin_bit_cast(bf16x8,
                   *(const uint4*)&w3f[(((size_t)(ks*NCT2 + ct)) << 9) + l*8]);
      #pragma unroll
      for (int rt = 0; rt < NRT; ++rt)
        acc2[rt][c] = __builtin_amdgcn_mfma_f32_16x16x32_bf16(a[rt], b, acc2[rt][c], 0, 0, 0);
    }
  }
  __syncthreads();   // all h2 reads done; smem free for fp32 spill

  // ---- epilogue2: spill C2 to LDS fp32; mark run starts ----
  #pragma unroll
  for (int c = 0; c < 2; ++c){
    int col = (wave*2 + c)*16 + lrow;
    #pragma unroll
    for (int rt = 0; rt < NRT; ++rt){
      #pragma unroll
      for (int r = 0; r < 4; ++r){
        int row = rt*16 + lq*4 + r;
        hsf[row*HSFS + col] = acc2[rt][c][r];
      }
    }
  }
  if (tid < EPB) sflag[tid] = (tid == 0) || (sdst[tid] != sdst[tid-1]);
  __syncthreads();

  // ---- block-level run-compressed scatter: one atomic per (run, col) ----
  {
    const int col = tid & 127;
    if (col < LAT){
      for (int s = tid >> 7; s < EPB; s += 2){
        if (!sflag[s]) continue;
        int d = sdst[s];
        if (d < 0) continue;
        float sum = hsf[s*HSFS + col];
        int r = s + 1;
        while (r < EPB && !sflag[r]){ sum += hsf[r*HSFS + col]; ++r; }
        atomicAdd(&nodeacc[(size_t)d*LAT + col], sum);
      }
    }
  }
  #undef HS
}

// x1b[n][j<100] = bf16(relu(acc/max(cnt,1) + (cnt>0?b3:0))), pad cols -> 0; re-zero acc.
__global__ void finalize_kernel(float* __restrict__ nodeacc, const int* __restrict__ hist,
                                const float* __restrict__ b3,
                                unsigned short* __restrict__ x1b){
  int idx = blockIdx.x*blockDim.x + threadIdx.x;
  if (idx < N_NODES*128){
    int n = idx >> 7, j = idx & 127;
    unsigned short o = 0;
    if (j < LAT){
      int c = hist[n];
      float v = nodeacc[(size_t)n*LAT + j] / fmaxf((float)c, 1.f);
      v += (c > 0) ? b3[j] : 0.f;
      o = f2bf_hw(relu_f(v));
      nodeacc[(size_t)n*LAT + j] = 0.f;
    }
    x1b[idx] = o;
  }
}

// segmented mean-pool: one block per graph, no atomics
__global__ __launch_bounds__(512) void pool_seg(const unsigned short* __restrict__ x1b,
                                                const int* __restrict__ gstart,
                                                float* __restrict__ pooled){
  __shared__ float buf[3][128];
  const int g = blockIdx.x;
  const int lo = gstart[g], hi = gstart[g+1];
  const int col = threadIdx.x & 127, q = threadIdx.x >> 7;
  float s = 0.f;
  for (int n = lo + q; n < hi; n += 4) s += bf2f(x1b[(size_t)n*128 + col]);
  if (q) buf[q-1][col] = s;
  __syncthreads();
  if (q == 0 && col < LAT){
    float tot = s + buf[0][col] + buf[1][col] + buf[2][col];
    pooled[g*LAT + col] = tot / fmaxf((float)(hi - lo), 1.f);
  }
}

__global__ __launch_bounds__(128) void head_kernel(
    const float* __restrict__ pooled,
    const float* __restrict__ u,
    const float* __restrict__ w1, const float* __restrict__ bb1,
    const float* __restrict__ w2, const float* __restrict__ bb2,
    const float* __restrict__ w3, const float* __restrict__ bb3,
    float* __restrict__ out){
  __shared__ float p[N_GRAPHS][LAT+GLOBAL_F];
  __shared__ float h1[N_GRAPHS][LAT];
  __shared__ float h2[N_GRAPHS][LAT];
  const int tid = threadIdx.x;
  for (int t = tid; t < N_GRAPHS*LAT; t += 128){
    int g = t / LAT, k = t - g*LAT;
    p[g][k] = pooled[t];
  }
  for (int t = tid; t < N_GRAPHS*GLOBAL_F; t += 128){
    int g = t / GLOBAL_F, c = t - g*GLOBAL_F;
    p[g][LAT + c] = u[t];
  }
  __syncthreads();
  for (int t = tid; t < N_GRAPHS*LAT; t += 128){
    int g = t / LAT, j = t - g*LAT;
    float s = bb1[j];
    for (int k = 0; k < LAT+GLOBAL_F; k++) s += p[g][k]*w1[(size_t)k*LAT + j];
    h1[g][j] = relu_f(s);
  }
  __syncthreads();
  for (int t = tid; t < N_GRAPHS*LAT; t += 128){
    int g = t / LAT, j = t - g*LAT;
    float s = bb2[j];
    for (int k = 0; k < LAT; k++) s += h1[g][k]*w2[(size_t)k*LAT + j];
    h2[g][j] = relu_f(s);
  }
  __syncthreads();
  for (int t = tid; t < N_GRAPHS; t += 128){
    float s = bb3[0];
    for (int k = 0; k < LAT; k++) s += h2[t][k]*w3[k];
    out[t] = s;
  }
}

extern "C" void kernel_launch(void* const* d_in, const int* in_sizes, int n_in,
                              void* d_out, int out_size, void* d_ws, size_t ws_size,
                              hipStream_t stream){
  (void)in_sizes; (void)n_in; (void)out_size; (void)ws_size;
  const float* x     = (const float*)d_in[0];
  const int*   ei    = (const int*)d_in[1];
  const int*   batch = (const int*)d_in[2];
  const float* u     = (const float*)d_in[3];
  const float* l0_w1 = (const float*)d_in[4];  const float* l0_b1 = (const float*)d_in[5];
  const float* l0_w2 = (const float*)d_in[6];  const float* l0_b2 = (const float*)d_in[7];
  const float* l0_w3 = (const float*)d_in[8];  const float* l0_b3 = (const float*)d_in[9];
  const float* l1_w1 = (const float*)d_in[10]; const float* l1_b1 = (const float*)d_in[11];
  const float* l1_w2 = (const float*)d_in[12]; const float* l1_b2 = (const float*)d_in[13];
  const float* l1_w3 = (const float*)d_in[14]; const float* l1_b3 = (const float*)d_in[15];
  const float* lin_w1= (const float*)d_in[16]; const float* lin_b1= (const float*)d_in[17];
  const float* lin_w2= (const float*)d_in[18]; const float* lin_b2= (const float*)d_in[19];
  const float* lin_w3= (const float*)d_in[20]; const float* lin_b3= (const float*)d_in[21];

  char* wsb = (char*)d_ws;
  const size_t UV_BYTES  = (size_t)N_NODES*HIDP*sizeof(unsigned short);
  const size_t W1F0_ELEMS = (size_t)1*40*512;
  const size_t W1F1_ELEMS = (size_t)4*40*512;

  unsigned short* Ub   = (unsigned short*)wsb;  wsb += UV_BYTES;
  unsigned short* Vb   = (unsigned short*)wsb;  wsb += UV_BYTES;
  unsigned short* w2f0 = (unsigned short*)wsb;  wsb += (size_t)W2F_ELEMS*2;
  unsigned short* w3f0 = (unsigned short*)wsb;  wsb += (size_t)W3F_ELEMS*2;
  unsigned short* w2f1 = (unsigned short*)wsb;  wsb += (size_t)W2F_ELEMS*2;
  unsigned short* w3f1 = (unsigned short*)wsb;  wsb += (size_t)W3F_ELEMS*2;
  unsigned short* w1f0 = (unsigned short*)wsb;  wsb += W1F0_ELEMS*2;
  unsigned short* w1f1 = (unsigned short*)wsb;  wsb += W1F1_ELEMS*2;
  float* b1p0 = (float*)wsb;                    wsb += HIDP*4;
  float* b2p0 = (float*)wsb;                    wsb += HIDP*4;
  float* b1p1 = (float*)wsb;                    wsb += HIDP*4;
  float* b2p1 = (float*)wsb;                    wsb += HIDP*4;
  unsigned short* xb0 = (unsigned short*)wsb;   wsb += (size_t)N_NODES*32*2;
  unsigned short* x1b = (unsigned short*)wsb;   wsb += (size_t)N_NODES*128*2;
  // contiguous zero region: nodeacc + hist
  float* nodeacc = (float*)wsb;                 wsb += (size_t)N_NODES*LAT*4;
  int*   hist    = (int*)wsb;                   wsb += (size_t)N_NODES*4;
  int*   woff    = (int*)wsb;                   wsb += (size_t)N_NODES*4;
  int*   es      = (int*)wsb;                   wsb += (size_t)N_EDGES*4;
  int*   ed      = (int*)wsb;                   wsb += (size_t)N_EDGES*4;
  int*   gstart  = (int*)wsb;                   wsb += 64*4;
  float* pooled  = (float*)wsb;                 wsb += (size_t)N_GRAPHS*LAT*4;

  {
    int zn = N_NODES*LAT + N_NODES;   // nodeacc + hist
    hipLaunchKernelGGL(zero_kernel, dim3((zn+255)/256), dim3(256), 0, stream, nodeacc, zn);
  }
  hipLaunchKernelGGL(hist_kernel, dim3((N_EDGES+255)/256), dim3(256), 0, stream, ei, hist);
  hipLaunchKernelGGL(scan_kernel, dim3(1), dim3(256), 0, stream, hist, woff);
  hipLaunchKernelGGL(sort_kernel, dim3((N_EDGES+255)/256), dim3(256), 0, stream,
                     ei, woff, es, ed);
  hipLaunchKernelGGL(gstart_kernel, dim3((N_NODES+255)/256), dim3(256), 0, stream,
                     batch, gstart);

  // weight / bias prep
  {
    int total = 2*W2F_ELEMS + 2*W3F_ELEMS;
    hipLaunchKernelGGL(pack_all, dim3((total+255)/256), dim3(256), 0, stream,
                       l0_w2, l0_w3, l1_w2, l1_w3, w2f0, w3f0, w2f1, w3f1);
  }
  hipLaunchKernelGGL(pack_w1frag<NODE_F>, dim3(((int)W1F0_ELEMS+255)/256), dim3(256), 0, stream,
                     l0_w1, w1f0, (int)W1F0_ELEMS);
  hipLaunchKernelGGL(pack_w1frag<LAT>, dim3(((int)W1F1_ELEMS+255)/256), dim3(256), 0, stream,
                     l1_w1, w1f1, (int)W1F1_ELEMS);
  hipLaunchKernelGGL(pad_bias4, dim3(2), dim3(256), 0, stream,
                     l0_b1, l0_b2, l1_b1, l1_b2, b1p0, b2p0, b1p1, b2p1);
  hipLaunchKernelGGL(cvt_x0, dim3((N_NODES*32+255)/256), dim3(256), 0, stream, x, xb0);

  const int NGB = (N_NODES + 63)/64;
  const int NEB = (N_EDGES + EPB - 1)/EPB;   // 8334

  // layer 0
  hipLaunchKernelGGL(node_gemm<32>, dim3(NGB), dim3(256), 0, stream, xb0, w1f0, Ub, Vb);
  hipLaunchKernelGGL(edge_mfma, dim3(NEB), dim3(256), 0, stream,
                     es, ed, Ub, Vb, b1p0, w2f0, b2p0, w3f0, nodeacc);
  hipLaunchKernelGGL(finalize_kernel, dim3((N_NODES*128+255)/256), dim3(256), 0, stream,
                     nodeacc, hist, l0_b3, x1b);

  // layer 1
  hipLaunchKernelGGL(node_gemm<128>, dim3(NGB), dim3(256), 0, stream, x1b, w1f1, Ub, Vb);
  hipLaunchKernelGGL(edge_mfma, dim3(NEB), dim3(256), 0, stream,
                     es, ed, Ub, Vb, b1p1, w2f1, b2p1, w3f1, nodeacc);
  hipLaunchKernelGGL(finalize_kernel, dim3((N_NODES*128+255)/256), dim3(256), 0, stream,
                     nodeacc, hist, l1_b3, x1b);

  // pooling + head
  hipLaunchKernelGGL(pool_seg, dim3(N_GRAPHS), dim3(512), 0, stream, x1b, gstart, pooled);
  hipLaunchKernelGGL(head_kernel, dim3(1), dim3(128), 0, stream,
                     pooled, u, lin_w1, lin_b1, lin_w2, lin_b2, lin_w3, lin_b3,
                     (float*)d_out);
}

// Round 6
// 1494.850 us; speedup vs baseline: 1.0951x; 1.0951x over previous
//
#include <hip/hip_runtime.h>
#include <cstdint>
#include <cstddef>

#define N_NODES  50000
#define N_GRAPHS 32
#define NODE_F   16
#define GLOBAL_F 2
#define HID      300
#define LAT      100
#define N_EDGES  800000

#define HIDP 320            // padded K / hidden (multiple of 32)
#define LATP 128            // padded GEMM2 output cols
#define NCT1 (HIDP/16)      // 20 col-tiles GEMM1
#define NCT2 (LATP/16)      // 8  col-tiles GEMM2
#define NKS  (HIDP/32)      // 10 k-steps
#define EPB  64             // edges per block (N_EDGES divisible: 12500 blocks)
#define ROWP 66             // padded row count in chunked LDS layout
#define HSFS 132            // fp32 spill row stride (bank skew)

#define W2F_ELEMS 102400    /* NKS*NCT1*512 */
#define W3F_ELEMS 40960     /* NKS*NCT2*512 */
#define W1F0_ELEMS 20480    /* (32/32)*40*512 */
#define W1F1_ELEMS 81920    /* (128/32)*40*512 */

typedef __bf16 bf16x8 __attribute__((ext_vector_type(8)));
typedef float  f32x4  __attribute__((ext_vector_type(4)));

__device__ __forceinline__ float relu_f(float x){ return fmaxf(x, 0.f); }

__device__ __forceinline__ unsigned short f2bf(float x){   // RNE, for prep kernels
  unsigned int u = __float_as_uint(x);
  u = (u + 0x7FFFu + ((u >> 16) & 1u)) >> 16;
  return (unsigned short)u;
}
__device__ __forceinline__ unsigned short f2bf_hw(float x){ // hot path: hw convert
  __bf16 h = (__bf16)x;
  return __builtin_bit_cast(unsigned short, h);
}
__device__ __forceinline__ float bf2f(unsigned int h){
  return __uint_as_float(h << 16);
}

// ---------- fused prep: zero(nodeacc+hist) | pack w2/w3 (both layers) |
// ---------- pack w1' (both layers) | pad biases | cvt x0 ----------
__device__ __forceinline__ void pack_one(const float* __restrict__ w, int K, int N,
                                         int nct, unsigned short* __restrict__ out, int i){
  int j  = i & 7;
  int l  = (i >> 3) & 63;
  int t  = i >> 9;
  int ct = t % nct, ks = t / nct;
  int n = ct*16 + (l & 15);
  int k = ks*32 + ((l >> 4) << 3) + j;
  float v = (k < K && n < N) ? w[(size_t)k*N + n] : 0.f;
  out[i] = f2bf(v);
}

__device__ __forceinline__ void pack_w1_one(const float* __restrict__ w1, int F,
                                            unsigned short* __restrict__ out, int i){
  int j  = i & 7;
  int l  = (i >> 3) & 63;
  int t  = i >> 9;
  int ct = t % 40, ks = t / 40;
  int n = ct*16 + (l & 15);
  int k = ks*32 + ((l >> 4) << 3) + j;
  float v = 0.f;
  if (k < F){
    if (n < HIDP){ if (n < HID) v = w1[(size_t)k*HID + n] - w1[(size_t)(F+k)*HID + n]; }
    else { int nn = n - HIDP; if (nn < HID) v = w1[(size_t)(F+k)*HID + nn]; }
  }
  out[i] = f2bf(v);
}

#define PR_B0 (N_NODES*LAT + N_NODES)                    /* zero nodeacc+hist   */
#define PR_B1 (PR_B0 + 2*W2F_ELEMS + 2*W3F_ELEMS)        /* pack w2/w3 x2       */
#define PR_B2 (PR_B1 + W1F0_ELEMS)                       /* pack w1 layer0      */
#define PR_B3 (PR_B2 + W1F1_ELEMS)                       /* pack w1 layer1      */
#define PR_B4 (PR_B3 + HIDP)                             /* pad biases (x4)     */
#define PR_B5 (PR_B4 + N_NODES*32)                       /* cvt x0              */

__global__ void prep_kernel(
    int* __restrict__ zero_region,
    const float* __restrict__ w2a, const float* __restrict__ w3a,
    const float* __restrict__ w2b, const float* __restrict__ w3b,
    unsigned short* __restrict__ o2a, unsigned short* __restrict__ o3a,
    unsigned short* __restrict__ o2b, unsigned short* __restrict__ o3b,
    const float* __restrict__ w1a, unsigned short* __restrict__ o1a,
    const float* __restrict__ w1b, unsigned short* __restrict__ o1b,
    const float* __restrict__ ba0, const float* __restrict__ ba1,
    const float* __restrict__ ba2, const float* __restrict__ ba3,
    float* __restrict__ bo0, float* __restrict__ bo1,
    float* __restrict__ bo2, float* __restrict__ bo3,
    const float* __restrict__ x, unsigned short* __restrict__ xb){
  int i = blockIdx.x*blockDim.x + threadIdx.x;
  if (i < PR_B0){ zero_region[i] = 0; return; }
  if (i < PR_B1){
    int t = i - PR_B0;
    if (t < W2F_ELEMS) pack_one(w2a, HID, HID, NCT1, o2a, t);
    else if (t < W2F_ELEMS + W3F_ELEMS) pack_one(w3a, HID, LAT, NCT2, o3a, t - W2F_ELEMS);
    else if (t < 2*W2F_ELEMS + W3F_ELEMS) pack_one(w2b, HID, HID, NCT1, o2b, t - W2F_ELEMS - W3F_ELEMS);
    else pack_one(w3b, HID, LAT, NCT2, o3b, t - 2*W2F_ELEMS - W3F_ELEMS);
    return;
  }
  if (i < PR_B2){ pack_w1_one(w1a, NODE_F, o1a, i - PR_B1); return; }
  if (i < PR_B3){ pack_w1_one(w1b, LAT,    o1b, i - PR_B2); return; }
  if (i < PR_B4){
    int t = i - PR_B3;
    bo0[t] = (t < HID) ? ba0[t] : 0.f;
    bo1[t] = (t < HID) ? ba1[t] : 0.f;
    bo2[t] = (t < HID) ? ba2[t] : 0.f;
    bo3[t] = (t < HID) ? ba3[t] : 0.f;
    return;
  }
  if (i < PR_B5){
    int t = i - PR_B4;
    int n = t >> 5, c = t & 31;
    xb[t] = (c < NODE_F) ? f2bf(x[(size_t)n*NODE_F + c]) : 0;
    return;
  }
}

__global__ void hist_kernel(const int* __restrict__ ei, int* __restrict__ hist){
  int e = blockIdx.x*blockDim.x + threadIdx.x;
  if (e < N_EDGES) atomicAdd(&hist[ei[N_EDGES + e]], 1);
}

// single-block exclusive scan of hist -> woff (write cursor per node)
__global__ __launch_bounds__(256) void scan_kernel(const int* __restrict__ hist,
                                                   int* __restrict__ woff){
  __shared__ int part[256];
  const int t = threadIdx.x;
  const int CH = (N_NODES + 255) / 256;
  const int lo = t*CH, hi = (lo + CH < N_NODES) ? lo + CH : N_NODES;
  int s = 0;
  for (int i = lo; i < hi; ++i) s += hist[i];
  part[t] = s;
  __syncthreads();
  for (int d = 1; d < 256; d <<= 1){
    int v = (t >= d) ? part[t-d] : 0;
    __syncthreads();
    part[t] += v;
    __syncthreads();
  }
  int run = (t == 0) ? 0 : part[t-1];
  for (int i = lo; i < hi; ++i){ woff[i] = run; run += hist[i]; }
}

// counting-sort scatter (grouped by dst) + graph start offsets (sorted batch)
__global__ void sort_gstart(const int* __restrict__ ei, int* __restrict__ woff,
                            int* __restrict__ es, int* __restrict__ ed,
                            const int* __restrict__ batch, int* __restrict__ gstart){
  int e = blockIdx.x*blockDim.x + threadIdx.x;
  if (e < N_EDGES){
    int s = ei[e], d = ei[N_EDGES + e];
    int pos = atomicAdd(&woff[d], 1);
    es[pos] = s; ed[pos] = d;
  }
  if (e < N_NODES){
    int n = e;
    int b = batch[n];
    if (n == 0){ for (int g = 0; g <= b; ++g) gstart[g] = 0; }
    else {
      int bp = batch[n-1];
      for (int g = bp+1; g <= b; ++g) gstart[g] = n;
    }
    if (n == N_NODES-1){ for (int g = b+1; g <= N_GRAPHS; ++g) gstart[g] = N_NODES; }
  }
}

// node-level GEMM: [64 x KPAD] @ [KPAD x 640] -> Ub|Vb bf16
template<int KPAD>
__global__ __launch_bounds__(256) void node_gemm(
    const unsigned short* __restrict__ xb, const unsigned short* __restrict__ wf,
    unsigned short* __restrict__ Ub, unsigned short* __restrict__ Vb){
  constexpr int NCH = KPAD/8;
  __shared__ __align__(16) unsigned short at[NCH][66][8];
  const int tid = threadIdx.x;
  const int n0 = blockIdx.x*64;
  for (int i = tid; i < 64*NCH; i += 256){
    int row = i / NCH, c = i % NCH;
    int n = n0 + row; if (n >= N_NODES) n = N_NODES-1;
    *(uint4*)&at[c][row][0] = *(const uint4*)&xb[(size_t)n*KPAD + c*8];
  }
  __syncthreads();
  const int wave = tid >> 6, l = tid & 63;
  const int lrow = l & 15, lq = l >> 4;
  f32x4 acc[4][10];
  #pragma unroll
  for (int rt = 0; rt < 4; ++rt)
    #pragma unroll
    for (int c = 0; c < 10; ++c)
      acc[rt][c] = (f32x4){0.f,0.f,0.f,0.f};
  for (int ks = 0; ks < KPAD/32; ++ks){
    bf16x8 a[4];
    #pragma unroll
    for (int rt = 0; rt < 4; ++rt)
      a[rt] = __builtin_bit_cast(bf16x8, *(const uint4*)&at[4*ks + lq][16*rt + lrow][0]);
    #pragma unroll
    for (int c = 0; c < 10; ++c){
      int ct = wave*10 + c;
      bf16x8 b = __builtin_bit_cast(bf16x8,
                   *(const uint4*)&wf[(((size_t)(ks*40 + ct)) << 9) + l*8]);
      #pragma unroll
      for (int rt = 0; rt < 4; ++rt)
        acc[rt][c] = __builtin_amdgcn_mfma_f32_16x16x32_bf16(a[rt], b, acc[rt][c], 0, 0, 0);
    }
  }
  #pragma unroll
  for (int c = 0; c < 10; ++c){
    int col = (wave*10 + c)*16 + lrow;
    #pragma unroll
    for (int rt = 0; rt < 4; ++rt){
      #pragma unroll
      for (int r = 0; r < 4; ++r){
        int n = n0 + rt*16 + lq*4 + r;
        if (n < N_NODES){
          unsigned short hv = f2bf_hw(acc[rt][c][r]);
          if (col < HIDP) Ub[(size_t)n*HIDP + col] = hv;
          else            Vb[(size_t)n*HIDP + col - HIDP] = hv;
        }
      }
    }
  }
}

// Per 64-edge tile (edges sorted by dst): gather h1 -> LDS chunked; GEMM1; h2; GEMM2;
// in-place fp32 spill (reuses hs LDS) + block-level run-compressed atomic scatter.
__global__ __launch_bounds__(256, 3) void edge_mfma(
    const int* __restrict__ es, const int* __restrict__ ed,
    const unsigned short* __restrict__ U, const unsigned short* __restrict__ V,
    const float* __restrict__ b1p, const unsigned short* __restrict__ w2f,
    const float* __restrict__ b2p, const unsigned short* __restrict__ w3f,
    float* __restrict__ nodeacc){
  __shared__ __align__(16) unsigned char smem[(HIDP/8)*ROWP*8*2];  // 42,240 B
  __shared__ int sdst[EPB];
  __shared__ int sflag[EPB];
  unsigned short* hsb = (unsigned short*)smem;   // [40][ROWP][8] bf16 chunked
  float*          hsf = (float*)smem;            // [64][HSFS] fp32 spill (reuse)
  #define HS(c,row) (hsb + (((c)*ROWP + (row)) << 3))

  const int tid = threadIdx.x;
  const int e0 = blockIdx.x * EPB;           // N_EDGES % EPB == 0
  const int eL = tid & 63;
  const int mysrc = es[e0 + eL];
  const int mydst = ed[e0 + eL];
  if (tid < EPB) sdst[tid] = mydst;          // visible after first barrier

  // ---- gather + h1 ----
  const size_t ubase = (size_t)mydst*HIDP;
  const size_t vbase = (size_t)mysrc*HIDP;
  #pragma unroll
  for (int it = 0; it < 10; ++it){
    int c = (tid + it*256) >> 6;
    const uint4 uu = *(const uint4*)&U[ubase + c*8];
    const uint4 vv = *(const uint4*)&V[vbase + c*8];
    const float4 bl = *(const float4*)&b1p[c*8];
    const float4 bh = *(const float4*)&b1p[c*8 + 4];
    const unsigned int uarr[4] = {uu.x, uu.y, uu.z, uu.w};
    const unsigned int varr[4] = {vv.x, vv.y, vv.z, vv.w};
    const float barr[8] = {bl.x, bl.y, bl.z, bl.w, bh.x, bh.y, bh.z, bh.w};
    unsigned int ou[4];
    #pragma unroll
    for (int q = 0; q < 4; ++q){
      float f0 = relu_f(bf2f(uarr[q] & 0xFFFFu) + bf2f(varr[q] & 0xFFFFu) + barr[2*q]);
      float f1 = relu_f(bf2f(uarr[q] >> 16)     + bf2f(varr[q] >> 16)     + barr[2*q+1]);
      ou[q] = (unsigned int)f2bf_hw(f0) | ((unsigned int)f2bf_hw(f1) << 16);
    }
    *(uint4*)HS(c, eL) = make_uint4(ou[0], ou[1], ou[2], ou[3]);
  }
  __syncthreads();

  const int wave = tid >> 6, l = tid & 63;
  const int lrow = l & 15, lq = l >> 4;

  // ---- GEMM1: [64 x 320] = h1 @ w2 ----
  f32x4 acc1[4][5];
  #pragma unroll
  for (int rt = 0; rt < 4; ++rt)
    #pragma unroll
    for (int c = 0; c < 5; ++c)
      acc1[rt][c] = (f32x4){0.f,0.f,0.f,0.f};
  for (int ks = 0; ks < NKS; ++ks){
    bf16x8 a[4];
    #pragma unroll
    for (int rt = 0; rt < 4; ++rt)
      a[rt] = __builtin_bit_cast(bf16x8, *(const uint4*)HS(4*ks + lq, 16*rt + lrow));
    #pragma unroll
    for (int c = 0; c < 5; ++c){
      int ct = wave*5 + c;
      bf16x8 b = __builtin_bit_cast(bf16x8,
                   *(const uint4*)&w2f[(((size_t)(ks*NCT1 + ct)) << 9) + l*8]);
      #pragma unroll
      for (int rt = 0; rt < 4; ++rt)
        acc1[rt][c] = __builtin_amdgcn_mfma_f32_16x16x32_bf16(a[rt], b, acc1[rt][c], 0, 0, 0);
    }
  }
  __syncthreads();   // all h1 reads done

  // ---- epilogue1: h2 = relu(C1 + b2) -> hs ----
  #pragma unroll
  for (int c = 0; c < 5; ++c){
    int col = (wave*5 + c)*16 + lrow;
    float b2v = b2p[col];
    #pragma unroll
    for (int rt = 0; rt < 4; ++rt){
      #pragma unroll
      for (int r = 0; r < 4; ++r){
        int row = rt*16 + lq*4 + r;
        HS(col >> 3, row)[col & 7] = f2bf_hw(relu_f(acc1[rt][c][r] + b2v));
      }
    }
  }
  __syncthreads();

  // ---- GEMM2: [64 x 128] = h2 @ w3 ----
  f32x4 acc2[4][2];
  #pragma unroll
  for (int rt = 0; rt < 4; ++rt)
    #pragma unroll
    for (int c = 0; c < 2; ++c)
      acc2[rt][c] = (f32x4){0.f,0.f,0.f,0.f};
  for (int ks = 0; ks < NKS; ++ks){
    bf16x8 a[4];
    #pragma unroll
    for (int rt = 0; rt < 4; ++rt)
      a[rt] = __builtin_bit_cast(bf16x8, *(const uint4*)HS(4*ks + lq, 16*rt + lrow));
    #pragma unroll
    for (int c = 0; c < 2; ++c){
      int ct = wave*2 + c;
      bf16x8 b = __builtin_bit_cast(bf16x8,
                   *(const uint4*)&w3f[(((size_t)(ks*NCT2 + ct)) << 9) + l*8]);
      #pragma unroll
      for (int rt = 0; rt < 4; ++rt)
        acc2[rt][c] = __builtin_amdgcn_mfma_f32_16x16x32_bf16(a[rt], b, acc2[rt][c], 0, 0, 0);
    }
  }
  __syncthreads();   // all h2 reads done; smem free for fp32 spill

  // ---- epilogue2: spill C2 to LDS fp32 (reusing hs memory); mark run starts ----
  #pragma unroll
  for (int c = 0; c < 2; ++c){
    int col = (wave*2 + c)*16 + lrow;
    #pragma unroll
    for (int rt = 0; rt < 4; ++rt){
      #pragma unroll
      for (int r = 0; r < 4; ++r){
        int row = rt*16 + lq*4 + r;
        hsf[row*HSFS + col] = acc2[rt][c][r];
      }
    }
  }
  if (tid < EPB) sflag[tid] = (tid == 0) || (sdst[tid] != sdst[tid-1]);
  __syncthreads();

  // ---- block-level run-compressed scatter: one atomic per (run, col) ----
  {
    const int col = tid & 127;
    if (col < LAT){
      for (int s = tid >> 7; s < EPB; s += 2){
        if (!sflag[s]) continue;
        int d = sdst[s];
        float sum = hsf[s*HSFS + col];
        int r = s + 1;
        while (r < EPB && !sflag[r]){ sum += hsf[r*HSFS + col]; ++r; }
        atomicAdd(&nodeacc[(size_t)d*LAT + col], sum);
      }
    }
  }
  #undef HS
}

// x1b[n][j<100] = bf16(relu(acc/max(cnt,1) + (cnt>0?b3:0))), pad cols -> 0; re-zero acc.
__global__ void finalize_kernel(float* __restrict__ nodeacc, const int* __restrict__ hist,
                                const float* __restrict__ b3,
                                unsigned short* __restrict__ x1b){
  int idx = blockIdx.x*blockDim.x + threadIdx.x;
  if (idx < N_NODES*128){
    int n = idx >> 7, j = idx & 127;
    unsigned short o = 0;
    if (j < LAT){
      int c = hist[n];
      float v = nodeacc[(size_t)n*LAT + j] / fmaxf((float)c, 1.f);
      v += (c > 0) ? b3[j] : 0.f;
      o = f2bf_hw(relu_f(v));
      nodeacc[(size_t)n*LAT + j] = 0.f;
    }
    x1b[idx] = o;
  }
}

// segmented mean-pool: one block per graph, no atomics
__global__ __launch_bounds__(512) void pool_seg(const unsigned short* __restrict__ x1b,
                                                const int* __restrict__ gstart,
                                                float* __restrict__ pooled){
  __shared__ float buf[3][128];
  const int g = blockIdx.x;
  const int lo = gstart[g], hi = gstart[g+1];
  const int col = threadIdx.x & 127, q = threadIdx.x >> 7;
  float s = 0.f;
  for (int n = lo + q; n < hi; n += 4) s += bf2f(x1b[(size_t)n*128 + col]);
  if (q) buf[q-1][col] = s;
  __syncthreads();
  if (q == 0 && col < LAT){
    float tot = s + buf[0][col] + buf[1][col] + buf[2][col];
    pooled[g*LAT + col] = tot / fmaxf((float)(hi - lo), 1.f);
  }
}

__global__ __launch_bounds__(128) void head_kernel(
    const float* __restrict__ pooled,
    const float* __restrict__ u,
    const float* __restrict__ w1, const float* __restrict__ bb1,
    const float* __restrict__ w2, const float* __restrict__ bb2,
    const float* __restrict__ w3, const float* __restrict__ bb3,
    float* __restrict__ out){
  __shared__ float p[N_GRAPHS][LAT+GLOBAL_F];
  __shared__ float h1[N_GRAPHS][LAT];
  __shared__ float h2[N_GRAPHS][LAT];
  const int tid = threadIdx.x;
  for (int t = tid; t < N_GRAPHS*LAT; t += 128){
    int g = t / LAT, k = t - g*LAT;
    p[g][k] = pooled[t];
  }
  for (int t = tid; t < N_GRAPHS*GLOBAL_F; t += 128){
    int g = t / GLOBAL_F, c = t - g*GLOBAL_F;
    p[g][LAT + c] = u[t];
  }
  __syncthreads();
  for (int t = tid; t < N_GRAPHS*LAT; t += 128){
    int g = t / LAT, j = t - g*LAT;
    float s = bb1[j];
    for (int k = 0; k < LAT+GLOBAL_F; k++) s += p[g][k]*w1[(size_t)k*LAT + j];
    h1[g][j] = relu_f(s);
  }
  __syncthreads();
  for (int t = tid; t < N_GRAPHS*LAT; t += 128){
    int g = t / LAT, j = t - g*LAT;
    float s = bb2[j];
    for (int k = 0; k < LAT; k++) s += h1[g][k]*w2[(size_t)k*LAT + j];
    h2[g][j] = relu_f(s);
  }
  __syncthreads();
  for (int t = tid; t < N_GRAPHS; t += 128){
    float s = bb3[0];
    for (int k = 0; k < LAT; k++) s += h2[t][k]*w3[k];
    out[t] = s;
  }
}

extern "C" void kernel_launch(void* const* d_in, const int* in_sizes, int n_in,
                              void* d_out, int out_size, void* d_ws, size_t ws_size,
                              hipStream_t stream){
  (void)in_sizes; (void)n_in; (void)out_size; (void)ws_size;
  const float* x     = (const float*)d_in[0];
  const int*   ei    = (const int*)d_in[1];
  const int*   batch = (const int*)d_in[2];
  const float* u     = (const float*)d_in[3];
  const float* l0_w1 = (const float*)d_in[4];  const float* l0_b1 = (const float*)d_in[5];
  const float* l0_w2 = (const float*)d_in[6];  const float* l0_b2 = (const float*)d_in[7];
  const float* l0_w3 = (const float*)d_in[8];  const float* l0_b3 = (const float*)d_in[9];
  const float* l1_w1 = (const float*)d_in[10]; const float* l1_b1 = (const float*)d_in[11];
  const float* l1_w2 = (const float*)d_in[12]; const float* l1_b2 = (const float*)d_in[13];
  const float* l1_w3 = (const float*)d_in[14]; const float* l1_b3 = (const float*)d_in[15];
  const float* lin_w1= (const float*)d_in[16]; const float* lin_b1= (const float*)d_in[17];
  const float* lin_w2= (const float*)d_in[18]; const float* lin_b2= (const float*)d_in[19];
  const float* lin_w3= (const float*)d_in[20]; const float* lin_b3= (const float*)d_in[21];

  char* wsb = (char*)d_ws;
  const size_t UV_BYTES = (size_t)N_NODES*HIDP*sizeof(unsigned short);

  unsigned short* Ub   = (unsigned short*)wsb;  wsb += UV_BYTES;
  unsigned short* Vb   = (unsigned short*)wsb;  wsb += UV_BYTES;
  unsigned short* w2f0 = (unsigned short*)wsb;  wsb += (size_t)W2F_ELEMS*2;
  unsigned short* w3f0 = (unsigned short*)wsb;  wsb += (size_t)W3F_ELEMS*2;
  unsigned short* w2f1 = (unsigned short*)wsb;  wsb += (size_t)W2F_ELEMS*2;
  unsigned short* w3f1 = (unsigned short*)wsb;  wsb += (size_t)W3F_ELEMS*2;
  unsigned short* w1f0 = (unsigned short*)wsb;  wsb += (size_t)W1F0_ELEMS*2;
  unsigned short* w1f1 = (unsigned short*)wsb;  wsb += (size_t)W1F1_ELEMS*2;
  float* b1p0 = (float*)wsb;                    wsb += HIDP*4;
  float* b2p0 = (float*)wsb;                    wsb += HIDP*4;
  float* b1p1 = (float*)wsb;                    wsb += HIDP*4;
  float* b2p1 = (float*)wsb;                    wsb += HIDP*4;
  unsigned short* xb0 = (unsigned short*)wsb;   wsb += (size_t)N_NODES*32*2;
  unsigned short* x1b = (unsigned short*)wsb;   wsb += (size_t)N_NODES*128*2;
  // contiguous zero region: nodeacc + hist
  float* nodeacc = (float*)wsb;                 wsb += (size_t)N_NODES*LAT*4;
  int*   hist    = (int*)wsb;                   wsb += (size_t)N_NODES*4;
  int*   woff    = (int*)wsb;                   wsb += (size_t)N_NODES*4;
  int*   es      = (int*)wsb;                   wsb += (size_t)N_EDGES*4;
  int*   ed      = (int*)wsb;                   wsb += (size_t)N_EDGES*4;
  int*   gstart  = (int*)wsb;                   wsb += 64*4;
  float* pooled  = (float*)wsb;                 wsb += (size_t)N_GRAPHS*LAT*4;

  // fused prep: zero + all weight packs + biases + x0 convert
  hipLaunchKernelGGL(prep_kernel, dim3((PR_B5+255)/256), dim3(256), 0, stream,
                     (int*)nodeacc,
                     l0_w2, l0_w3, l1_w2, l1_w3, w2f0, w3f0, w2f1, w3f1,
                     l0_w1, w1f0, l1_w1, w1f1,
                     l0_b1, l0_b2, l1_b1, l1_b2, b1p0, b2p0, b1p1, b2p1,
                     x, xb0);
  hipLaunchKernelGGL(hist_kernel, dim3((N_EDGES+255)/256), dim3(256), 0, stream, ei, hist);
  hipLaunchKernelGGL(scan_kernel, dim3(1), dim3(256), 0, stream, hist, woff);
  hipLaunchKernelGGL(sort_gstart, dim3((N_EDGES+255)/256), dim3(256), 0, stream,
                     ei, woff, es, ed, batch, gstart);

  const int NGB = (N_NODES + 63)/64;
  const int NEB = N_EDGES/EPB;   // 12500

  // layer 0
  hipLaunchKernelGGL(node_gemm<32>, dim3(NGB), dim3(256), 0, stream, xb0, w1f0, Ub, Vb);
  hipLaunchKernelGGL(edge_mfma, dim3(NEB), dim3(256), 0, stream,
                     es, ed, Ub, Vb, b1p0, w2f0, b2p0, w3f0, nodeacc);
  hipLaunchKernelGGL(finalize_kernel, dim3((N_NODES*128+255)/256), dim3(256), 0, stream,
                     nodeacc, hist, l0_b3, x1b);

  // layer 1
  hipLaunchKernelGGL(node_gemm<128>, dim3(NGB), dim3(256), 0, stream, x1b, w1f1, Ub, Vb);
  hipLaunchKernelGGL(edge_mfma, dim3(NEB), dim3(256), 0, stream,
                     es, ed, Ub, Vb, b1p1, w2f1, b2p1, w3f1, nodeacc);
  hipLaunchKernelGGL(finalize_kernel, dim3((N_NODES*128+255)/256), dim3(256), 0, stream,
                     nodeacc, hist, l1_b3, x1b);

  // pooling + head
  hipLaunchKernelGGL(pool_seg, dim3(N_GRAPHS), dim3(512), 0, stream, x1b, gstart, pooled);
  hipLaunchKernelGGL(head_kernel, dim3(1), dim3(128), 0, stream,
                     pooled, u, lin_w1, lin_b1, lin_w2, lin_b2, lin_w3, lin_b3,
                     (float*)d_out);
}